// Round 1
// baseline (394.992 us; speedup 1.0000x reference)
//
#include <hip/hip_runtime.h>
#include <cstdint>

#define NN 1024
#define BB 32
#define LL 128
#define DE 16
#define HH 4
#define K1 4     // K+1 Chebyshev terms
#define BD 512   // BB*DE columns in the Clenshaw matmuls

// ---------------------------------------------------------------- Q/K projections
// Q[n][h][m] = sum_d psi_emb[n,d] * W_q[d,h,m]   (W layout (DE,H,DE) -> d*64 + h*16 + m)
__global__ __launch_bounds__(256) void qk_kernel(
    const float* __restrict__ psi_emb, const float* __restrict__ W_q,
    const float* __restrict__ W_k, float* __restrict__ Qbuf, float* __restrict__ Kbuf)
{
    const int idx = blockIdx.x * 256 + threadIdx.x;   // N*H*DE = 65536
    const int n = idx >> 6;
    const int hm = idx & 63;
    const float* e = psi_emb + n * DE;
    float q = 0.f, k = 0.f;
#pragma unroll
    for (int d = 0; d < DE; d++) {
        const float ev = e[d];
        q += ev * W_q[d * 64 + hm];
        k += ev * W_k[d * 64 + hm];
    }
    Qbuf[idx] = q;
    Kbuf[idx] = k;
}

// ---------------------------------------------------------------- blended adjacency
// One block per row i. Both softmaxes normalize over the same axis (j/m), so one
// pass computes A_base numerators + all H attention numerators into LDS, reduces
// the 5 sums, then writes A_eff[h][i][j] = alpha*base + (1-alpha)*attn (coalesced in j).
__global__ __launch_bounds__(256) void adj_kernel(
    const float* __restrict__ psi_emb, const float* __restrict__ psi_p,
    const float* __restrict__ alpha_p, const float* __restrict__ Qbuf,
    const float* __restrict__ Kbuf, float* __restrict__ A_eff)
{
    __shared__ float base_row[NN];
    __shared__ float attn_row[HH][NN];
    __shared__ float e_i[DE];
    __shared__ float Qi[64];
    __shared__ float red[256];
    __shared__ float sums[5];

    const int i = blockIdx.x;
    const int tid = threadIdx.x;
    if (tid < DE) e_i[tid] = psi_emb[i * DE + tid];
    if (tid >= 64 && tid < 128) Qi[tid - 64] = Qbuf[i * 64 + (tid - 64)];
    __syncthreads();

    const float psi = psi_p[0];
    float sb = 0.f, sa[HH] = {0.f, 0.f, 0.f, 0.f};
    for (int j = tid; j < NN; j += 256) {
        const float* ej = psi_emb + j * DE;
        float d2 = 0.f;
#pragma unroll
        for (int d = 0; d < DE; d++) { const float t = e_i[d] - ej[d]; d2 += t * t; }
        // softmax numerator of exp(-psi*d2); argument is in (0,1] so exp is safe unstabilized
        const float bnum = expf(expf(-psi * d2));
        base_row[j] = bnum;
        sb += bnum;
        const float* kj = Kbuf + j * 64;
#pragma unroll
        for (int h = 0; h < HH; h++) {
            float dot = 0.f;
#pragma unroll
            for (int m = 0; m < DE; m++) dot += Qi[h * DE + m] * kj[h * DE + m];
            const float an = expf(dot * 0.25f);   // scale = 1/sqrt(16); logits ~O(0.1), exp safe
            attn_row[h][j] = an;
            sa[h] += an;
        }
    }
    // deterministic tree reductions for the 5 sums
    float vals[5] = {sb, sa[0], sa[1], sa[2], sa[3]};
    for (int q = 0; q < 5; q++) {
        red[tid] = vals[q];
        __syncthreads();
        for (int s = 128; s > 0; s >>= 1) {
            if (tid < s) red[tid] += red[tid + s];
            __syncthreads();
        }
        if (tid == 0) sums[q] = red[0];
        __syncthreads();
    }
    const float alpha = 1.f / (1.f + expf(-alpha_p[0]));
    const float ib = alpha / sums[0];
    float ia[HH];
#pragma unroll
    for (int h = 0; h < HH; h++) ia[h] = (1.f - alpha) / sums[1 + h];
    for (int j = tid; j < NN; j += 256) {
        const float bn = base_row[j] * ib;
#pragma unroll
        for (int h = 0; h < HH; h++)
            A_eff[(size_t)(h * NN + i) * NN + j] = bn + attn_row[h][j] * ia[h];
    }
}

// ---------------------------------------------------------------- G stage
// G[h][k][m][b*16+d] = sum_l x[b,m,l] * F_w[h,d,k,l].
// Block = (b, 8 consecutive nodes m). Thread t=(k,h,d) so 16 consecutive lanes (d)
// write 64B-contiguous chunks of the bd column dimension.
__global__ __launch_bounds__(256) void g_kernel(
    const float* __restrict__ x, const float* __restrict__ F_w, float* __restrict__ G)
{
    const int bid = blockIdx.x;       // BB*NN/8 = 4096
    const int b = bid >> 7;
    const int m0 = (bid & 127) * 8;
    __shared__ float xs[8][LL];
    const int tid = threadIdx.x;
    for (int idx = tid; idx < 8 * LL; idx += 256) {
        const int mm = idx >> 7, l = idx & 127;
        xs[mm][l] = x[((size_t)b * NN + m0 + mm) * LL + l];
    }
    __syncthreads();
    const int k = tid >> 6, hh = (tid >> 4) & 3, d = tid & 15;
    const float* f = F_w + (size_t)((hh * DE + d) * K1 + k) * LL;
    float acc[8] = {};
    for (int l = 0; l < LL; l += 4) {
        const float4 fv = *(const float4*)(f + l);
#pragma unroll
        for (int mm = 0; mm < 8; mm++)
            acc[mm] += fv.x * xs[mm][l] + fv.y * xs[mm][l + 1] +
                       fv.z * xs[mm][l + 2] + fv.w * xs[mm][l + 3];
    }
    const size_t base = (size_t)(hh * K1 + k) * NN * BD + (size_t)b * DE + d;
#pragma unroll
    for (int mm = 0; mm < 8; mm++) G[base + (size_t)(m0 + mm) * BD] = acc[mm];
}

// ---------------------------------------------------------------- Clenshaw GEMM
// O = scale*(A @ B) + pc*P + qc*Q  per head (blockIdx.z). A: (N,N) row-major,
// B/P/Q/O: (N,512) row-major. 64x64 tile, TK=16, 256 threads, 4x4 micro-tile.
__global__ __launch_bounds__(256) void gemm_ep(
    const float* __restrict__ Abase,
    const float* __restrict__ Bbase, size_t sB,
    const float* __restrict__ Pbase, size_t sP,
    const float* __restrict__ Qbase, size_t sQ,
    float* __restrict__ Obase, size_t sO,
    float scale, float pc, float qc)
{
    const int h = blockIdx.z;
    const float* A  = Abase + (size_t)h * NN * NN;
    const float* Bm = Bbase + (size_t)h * sB;
    const float* P  = Pbase + (size_t)h * sP;
    const float* Q  = Qbase + (size_t)h * sQ;
    float* O        = Obase + (size_t)h * sO;

    const int c0 = blockIdx.x * 64;
    const int n0 = blockIdx.y * 64;

    __shared__ float As[16][64];   // [k][row]
    __shared__ float Bs[16][64];   // [k][col]

    const int tid = threadIdx.x;
    const int tx = tid & 15, ty = tid >> 4;
    const int ar = tid >> 2;          // 0..63 row in A tile
    const int ak = (tid & 3) * 4;     // 0,4,8,12 k within tile
    const int bk = tid >> 4;          // 0..15 k
    const int bc = (tid & 15) * 4;    // 0..60 col

    float acc[4][4] = {};

    for (int k0 = 0; k0 < NN; k0 += 16) {
        const float4 av = *(const float4*)(A  + (size_t)(n0 + ar) * NN + k0 + ak);
        const float4 bv = *(const float4*)(Bm + (size_t)(k0 + bk) * BD + c0 + bc);
        __syncthreads();
        As[ak + 0][ar] = av.x;
        As[ak + 1][ar] = av.y;
        As[ak + 2][ar] = av.z;
        As[ak + 3][ar] = av.w;
        *(float4*)(&Bs[bk][bc]) = bv;
        __syncthreads();
#pragma unroll
        for (int kk = 0; kk < 16; kk++) {
            const float4 a = *(const float4*)(&As[kk][ty * 4]);
            const float4 b = *(const float4*)(&Bs[kk][tx * 4]);
            acc[0][0] += a.x * b.x; acc[0][1] += a.x * b.y; acc[0][2] += a.x * b.z; acc[0][3] += a.x * b.w;
            acc[1][0] += a.y * b.x; acc[1][1] += a.y * b.y; acc[1][2] += a.y * b.z; acc[1][3] += a.y * b.w;
            acc[2][0] += a.z * b.x; acc[2][1] += a.z * b.y; acc[2][2] += a.z * b.z; acc[2][3] += a.z * b.w;
            acc[3][0] += a.w * b.x; acc[3][1] += a.w * b.y; acc[3][2] += a.w * b.z; acc[3][3] += a.w * b.w;
        }
    }
#pragma unroll
    for (int i = 0; i < 4; i++) {
        const size_t row = n0 + ty * 4 + i;
        const size_t off = row * BD + c0 + tx * 4;
        const float4 p = *(const float4*)(P + off);
        const float4 q = *(const float4*)(Q + off);
        float4 o;
        o.x = scale * acc[i][0] + pc * p.x + qc * q.x;
        o.y = scale * acc[i][1] + pc * p.y + qc * q.y;
        o.z = scale * acc[i][2] + pc * p.z + qc * q.z;
        o.w = scale * acc[i][3] + pc * p.w + qc * q.w;
        *(float4*)(O + off) = o;
    }
}

// ---------------------------------------------------------------- final contraction
// out[b,n] = sum_h mix_w[h] * ( sum_d e[n,d]*(S[h][n][b*16+d] + f_b[h,d]) )
__global__ __launch_bounds__(256) void out_kernel(
    const float* __restrict__ psi_emb, const float* __restrict__ f_b,
    const float* __restrict__ head_mix, const float* __restrict__ S,
    float* __restrict__ out)
{
    const int id = blockIdx.x * 256 + threadIdx.x;  // id = b*N + n
    const int n = id & (NN - 1);
    const int b = id >> 10;
    const float hm0 = head_mix[0], hm1 = head_mix[1], hm2 = head_mix[2], hm3 = head_mix[3];
    const float mx = fmaxf(fmaxf(hm0, hm1), fmaxf(hm2, hm3));
    const float w0 = expf(hm0 - mx), w1 = expf(hm1 - mx), w2 = expf(hm2 - mx), w3 = expf(hm3 - mx);
    const float isum = 1.f / (w0 + w1 + w2 + w3);
    const float mw[4] = {w0 * isum, w1 * isum, w2 * isum, w3 * isum};
    float e[DE];
#pragma unroll
    for (int d = 0; d < DE; d++) e[d] = psi_emb[n * DE + d];
    float total = 0.f;
#pragma unroll
    for (int h = 0; h < HH; h++) {
        const float* sp = S + ((size_t)h * NN + n) * BD + b * DE;
        const float* fb = f_b + h * DE;
        float acc = 0.f;
#pragma unroll
        for (int d = 0; d < DE; d++) acc += e[d] * (sp[d] + fb[d]);
        total += mw[h] * acc;
    }
    out[id] = total;
}

extern "C" void kernel_launch(void* const* d_in, const int* in_sizes, int n_in,
                              void* d_out, int out_size, void* d_ws, size_t ws_size,
                              hipStream_t stream)
{
    const float* x          = (const float*)d_in[0];
    const float* psi_emb    = (const float*)d_in[1];
    const float* psi        = (const float*)d_in[2];
    const float* W_q        = (const float*)d_in[3];
    const float* W_k        = (const float*)d_in[4];
    const float* attn_alpha = (const float*)d_in[5];
    const float* F_w        = (const float*)d_in[6];
    const float* f_b        = (const float*)d_in[7];
    const float* head_mix   = (const float*)d_in[8];
    float* out = (float*)d_out;

    float* ws = (float*)d_ws;
    const size_t NS = (size_t)NN * BD;            // 524288 floats per (h) slab
    float* Qbuf  = ws;                            // 65536
    float* Kbuf  = Qbuf + (size_t)NN * HH * DE;   // 65536
    float* A_eff = Kbuf + (size_t)NN * HH * DE;   // H*N*N = 4194304
    float* G     = A_eff + (size_t)HH * NN * NN;  // H*K1*N*BD = 8388608
    float* b2    = G + (size_t)HH * K1 * NS;      // H*N*BD
    float* b1    = b2 + (size_t)HH * NS;
    float* Sf    = b1 + (size_t)HH * NS;
    const size_t need_bytes = (size_t)((Sf + (size_t)HH * NS) - ws) * sizeof(float);
    if (ws_size < need_bytes) return;  // fail loudly via wrong output rather than corrupt

    qk_kernel<<<NN * HH * DE / 256, 256, 0, stream>>>(psi_emb, W_q, W_k, Qbuf, Kbuf);
    adj_kernel<<<NN, 256, 0, stream>>>(psi_emb, psi, attn_alpha, Qbuf, Kbuf, A_eff);
    g_kernel<<<BB * NN / 8, 256, 0, stream>>>(x, F_w, G);

    const dim3 gg(BD / 64, NN / 64, HH);
    // Clenshaw: b2 = G2 + 2*A@G3
    gemm_ep<<<gg, 256, 0, stream>>>(A_eff, G + 3 * NS, K1 * NS, G + 2 * NS, K1 * NS,
                                    G + 2 * NS, K1 * NS, b2, NS, 2.f, 1.f, 0.f);
    // b1 = G1 + 2*A@b2 - G3
    gemm_ep<<<gg, 256, 0, stream>>>(A_eff, b2, NS, G + 1 * NS, K1 * NS,
                                    G + 3 * NS, K1 * NS, b1, NS, 2.f, 1.f, -1.f);
    // Sf = G0 + A@b1 - b2
    gemm_ep<<<gg, 256, 0, stream>>>(A_eff, b1, NS, G, K1 * NS,
                                    b2, NS, Sf, NS, 1.f, 1.f, -1.f);

    out_kernel<<<BB * NN / 256, 256, 0, stream>>>(psi_emb, f_b, head_mix, Sf, out);
}